// Round 2
// baseline (256.044 us; speedup 1.0000x reference)
//
#include <hip/hip_runtime.h>
#include <stdint.h>
#include <stddef.h>

// CliffordLinear as one fused bf16 GEMM (A staged fp32 -> cvt in-register):
//   out[b, o*8+l] = sum_{i,k} X[b, i*8+k] * Wt[o*8+l, i*8+k] + bias[o*8+l]
//   Wt[(o,l),(i,k)] = sum_j cayley[j,k,l] * W[o,i,j]
// M=8192, N=2048, K=2048. fp32 X read directly (no cast kernel).

typedef __bf16 bf16x8 __attribute__((ext_vector_type(8)));
typedef float  f32x4  __attribute__((ext_vector_type(4)));

#define BM 128
#define BN 128
#define BK 32

__device__ __forceinline__ void async_copy16(void* lds_dst, const void* g_src) {
    __builtin_amdgcn_global_load_lds(
        (__attribute__((address_space(1))) void*)g_src,
        (__attribute__((address_space(3))) void*)lds_dst,
        16, 0, 0);
}

// ---------------- kernel 1: fold Cayley into weight ----------------
// Wt[n][kk] (bf16, [N][K]) with n=o*8+l, kk=i*8+k:
//   Wt = sum_j cayley[j*64 + k*8 + l] * W[o*Cin*8 + i*8 + j]
__global__ __launch_bounds__(256) void build_wt_kernel(
    const float* __restrict__ W,
    const float* __restrict__ cayley,
    __bf16* __restrict__ Wt,
    int Cin, int Cout)
{
    __shared__ float Cay[512];
    for (int t = threadIdx.x; t < 512; t += 256) Cay[t] = cayley[t];
    __syncthreads();

    int flat = blockIdx.x * 256 + threadIdx.x;   // flat = n*Cin + i
    int total = Cout * 8 * Cin;
    if (flat >= total) return;
    int i = flat % Cin;
    int n = flat / Cin;
    int o = n >> 3, l = n & 7;

    const float* wrow = W + ((size_t)o * Cin + i) * 8;
    float w8[8];
    #pragma unroll
    for (int j = 0; j < 8; ++j) w8[j] = wrow[j];

    bf16x8 outv;
    #pragma unroll
    for (int k = 0; k < 8; ++k) {
        float s = 0.f;
        #pragma unroll
        for (int j = 0; j < 8; ++j) s += Cay[j * 64 + k * 8 + l] * w8[j];
        outv[k] = (__bf16)s;
    }
    *(bf16x8*)(Wt + (size_t)n * (Cin * 8) + i * 8) = outv;
}

// ---------------- kernel 2: fused GEMM, C = cvt_bf16(A_f32) * Bt^T + bias ----
// X  : [M][K] fp32 (row-major)  -- staged to LDS as fp32, cvt after ds_read
// Bt : [N][K] bf16 (row-major)
// C  : [M][N] fp32
// LDS XOR-swizzle on the staging GLOBAL offsets (global_load_lds scatter is
// wave-uniform-base + lane*16, so the swizzle must ride on the src address):
//   A: physical float4-group p of row r holds global group p ^ (r & 7)
//   B: physical bf16x8-quad  c of row r holds global quad  c ^ ((r>>1) & 3)
// -> all fragment ds_read_b128 patterns become 2-way bank aliasing (free).
__global__ __launch_bounds__(256) void gemm_fused_kernel(
    const float* __restrict__ X,
    const __bf16* __restrict__ Bt,
    const float*  __restrict__ bias,
    float* __restrict__ C,
    int M, int N, int K)
{
    __shared__ __align__(16) float  As[BM * BK];   // 16 KB, swizzled [128][32] f32
    __shared__ __align__(16) __bf16 Bs[BN * BK];   // 8 KB,  swizzled [128][32] bf16

    const int tid  = threadIdx.x;
    const int wave = tid >> 6;
    const int lane = tid & 63;
    const int quad = lane >> 4;   // 0..3
    const int l16  = lane & 15;   // 0..15

    // --- XCD-aware swizzle: all 16 N-blocks of an M-band share bid%8 -> same XCD L2
    const int bid   = blockIdx.x;                    // 0..1023
    const int band  = (bid & 7) + ((bid >> 7) << 3); // 0..63
    const int ncol  = (bid >> 3) & 15;               // 0..15
    const int mBase = band * BM;
    const int nBase = ncol * BN;

    // --- A staging: fp32 rows of 128 B; 1 KB chunk = 8 rows; wave w -> chunks 4w..4w+3
    const int arow = lane >> 3;            // 0..7 row within chunk
    const int agrp = (lane & 7) ^ arow;    // swizzled global float4-group 0..7

    const float* gA0 = X + (size_t)(mBase + (4 * wave + 0) * 8 + arow) * K + agrp * 4;
    const float* gA1 = X + (size_t)(mBase + (4 * wave + 1) * 8 + arow) * K + agrp * 4;
    const float* gA2 = X + (size_t)(mBase + (4 * wave + 2) * 8 + arow) * K + agrp * 4;
    const float* gA3 = X + (size_t)(mBase + (4 * wave + 3) * 8 + arow) * K + agrp * 4;
    float* lA0 = As + (4 * wave + 0) * 256;   // 256 f32 = 1 KB per chunk
    float* lA1 = As + (4 * wave + 1) * 256;
    float* lA2 = As + (4 * wave + 2) * 256;
    float* lA3 = As + (4 * wave + 3) * 256;

    // --- B staging: bf16 rows of 64 B; 1 KB chunk = 16 rows; wave w -> chunks 2w,2w+1
    const int brow = lane >> 2;                        // 0..15
    const int bgrp = (lane & 3) ^ ((brow >> 1) & 3);   // swizzled bf16x8-quad 0..3

    const __bf16* gB0 = Bt + (size_t)(nBase + (2 * wave + 0) * 16 + brow) * K + bgrp * 8;
    const __bf16* gB1 = Bt + (size_t)(nBase + (2 * wave + 1) * 16 + brow) * K + bgrp * 8;
    __bf16* lB0 = Bs + (2 * wave + 0) * 512;
    __bf16* lB1 = Bs + (2 * wave + 1) * 512;

    // --- compute assignment: wave quadrant (64x64), 4x4 grid of 16x16 MFMA tiles
    const int wm = (wave >> 1) * 64;
    const int wn = (wave & 1) * 64;

    const int sA    = l16 & 7;                    // A swizzle key (row & 7)
    const int offA0 = ((2 * quad)     ^ sA) * 4;  // float offset of lo half
    const int offA1 = ((2 * quad + 1) ^ sA) * 4;  // float offset of hi half
    const int tB    = (l16 >> 1) & 3;             // B swizzle key
    const int offB  = (quad ^ tB) * 8;            // bf16 element offset

    const float*  fragAbase = As + (size_t)(wm + l16) * BK;  // row stride 32 f32
    const __bf16* fragBbase = Bs + (size_t)(wn + l16) * BK;  // row stride 32 bf16

    f32x4 acc[4][4] = {};

    for (int k0 = 0; k0 < K; k0 += BK) {
        __syncthreads();   // prior iteration's LDS reads done
        async_copy16(lA0, gA0 + k0);
        async_copy16(lA1, gA1 + k0);
        async_copy16(lA2, gA2 + k0);
        async_copy16(lA3, gA3 + k0);
        async_copy16(lB0, gB0 + k0);
        async_copy16(lB1, gB1 + k0);
        __syncthreads();   // vmcnt(0) drained before barrier by compiler

        bf16x8 af[4], bfr[4];
        #pragma unroll
        for (int mt = 0; mt < 4; ++mt) {
            const float* p = fragAbase + mt * 16 * BK;
            f32x4 lo = *(const f32x4*)(p + offA0);
            f32x4 hi = *(const f32x4*)(p + offA1);
            bf16x8 v;
            v[0] = (__bf16)lo[0]; v[1] = (__bf16)lo[1];
            v[2] = (__bf16)lo[2]; v[3] = (__bf16)lo[3];
            v[4] = (__bf16)hi[0]; v[5] = (__bf16)hi[1];
            v[6] = (__bf16)hi[2]; v[7] = (__bf16)hi[3];
            af[mt] = v;
        }
        #pragma unroll
        for (int nt = 0; nt < 4; ++nt)
            bfr[nt] = *(const bf16x8*)(fragBbase + nt * 16 * BK + offB);

        #pragma unroll
        for (int mt = 0; mt < 4; ++mt)
            #pragma unroll
            for (int nt = 0; nt < 4; ++nt)
                acc[mt][nt] = __builtin_amdgcn_mfma_f32_16x16x32_bf16(
                    af[mt], bfr[nt], acc[mt][nt], 0, 0, 0);
    }

    // --- epilogue: C/D layout col = lane&15, row = quad*4 + reg
    float bv[4];
    #pragma unroll
    for (int nt = 0; nt < 4; ++nt)
        bv[nt] = bias[nBase + wn + nt * 16 + l16];

    #pragma unroll
    for (int mt = 0; mt < 4; ++mt) {
        #pragma unroll
        for (int nt = 0; nt < 4; ++nt) {
            const int col = nBase + wn + nt * 16 + l16;
            #pragma unroll
            for (int r = 0; r < 4; ++r) {
                const int row = mBase + wm + mt * 16 + quad * 4 + r;
                C[(size_t)row * N + col] = acc[mt][nt][r] + bv[nt];
            }
        }
    }
}

extern "C" void kernel_launch(void* const* d_in, const int* in_sizes, int n_in,
                              void* d_out, int out_size, void* d_ws, size_t ws_size,
                              hipStream_t stream) {
    const float* x      = (const float*)d_in[0];  // [B][Cin][8]
    const float* weight = (const float*)d_in[1];  // [Cout][Cin][8]
    const float* bias   = (const float*)d_in[2];  // [Cout][8]
    const float* cayley = (const float*)d_in[3];  // [8][8][8]
    float* out = (float*)d_out;                   // [B][Cout][8]

    const int Cout = in_sizes[2] / 8;
    const int Cin  = in_sizes[1] / (Cout * 8);
    const int Bm   = in_sizes[0] / (Cin * 8);
    const int M = Bm;          // 8192
    const int N = Cout * 8;    // 2048
    const int K = Cin * 8;     // 2048

    __bf16* Wt = (__bf16*)d_ws;   // N*K bf16 = 8 MB

    // 1) fold cayley into weight -> Wt [N][K] bf16
    int totalWt = N * Cin;
    build_wt_kernel<<<(totalWt + 255) / 256, 256, 0, stream>>>(weight, cayley, Wt, Cin, Cout);

    // 2) fused GEMM (reads X fp32 directly)
    int grid = (M / BM) * (N / BN);   // 64 * 16 = 1024
    gemm_fused_kernel<<<grid, 256, 0, stream>>>(x, Wt, bias, out, M, N, K);
}

// Round 3
// 199.895 us; speedup vs baseline: 1.2809x; 1.2809x over previous
//
#include <hip/hip_runtime.h>
#include <stdint.h>
#include <stddef.h>

// CliffordLinear as one bf16 GEMM:
//   out[b, o*8+l] = sum_{i,k} X[b, i*8+k] * Wt[o*8+l, i*8+k] + bias[o*8+l]
//   Wt[(o,l),(i,k)] = sum_j cayley[j,k,l] * W[o,i,j]
// M=8192, N=2048, K=2048. bf16 MFMA, fp32 accumulate.
//
// R3 structure: round-1 proven GEMM base (bf16 A pre-cast, global_load_lds
// width-16 staging, 128x128 tile) + BK=64 (halves barrier count: 32 iters),
// two k-half subphases per iter to keep frag registers flat, XOR group
// swizzle on staging SOURCE addresses (rows are 32 words at BK=64 -> naive
// reads would be 16-way bank conflicted; swizzle makes them 2-way = free),
// XCD band swizzle for A-band L2 locality.

typedef __bf16 bf16x8 __attribute__((ext_vector_type(8)));
typedef float  f32x4  __attribute__((ext_vector_type(4)));

#define BM 128
#define BN 128
#define BK 64

__device__ __forceinline__ void async_copy16(void* lds_dst, const void* g_src) {
    // global -> LDS direct copy, 16B/lane; dest is wave-uniform base, HW
    // scatters lane i to base + i*16.
    __builtin_amdgcn_global_load_lds(
        (__attribute__((address_space(1))) void*)g_src,
        (__attribute__((address_space(3))) void*)lds_dst,
        16, 0, 0);
}

// ---------------- kernel 1: fp32 -> bf16 cast of X ----------------
__global__ __launch_bounds__(256) void cast_bf16_kernel(
    const float* __restrict__ in, __bf16* __restrict__ out, long n)
{
    long i = ((long)blockIdx.x * 256 + threadIdx.x) * 8;
    if (i + 8 <= n) {
        const f32x4* p = (const f32x4*)(in + i);
        f32x4 v0 = p[0];
        f32x4 v1 = p[1];
        bf16x8 o;
        o[0] = (__bf16)v0[0]; o[1] = (__bf16)v0[1];
        o[2] = (__bf16)v0[2]; o[3] = (__bf16)v0[3];
        o[4] = (__bf16)v1[0]; o[5] = (__bf16)v1[1];
        o[6] = (__bf16)v1[2]; o[7] = (__bf16)v1[3];
        *(bf16x8*)(out + i) = o;
    }
}

// ---------------- kernel 2: fold Cayley into weight ----------------
// Wt[n][kk] (bf16, [N][K]) with n=o*8+l, kk=i*8+k:
//   Wt = sum_j cayley[j*64 + k*8 + l] * W[o*Cin*8 + i*8 + j]
__global__ __launch_bounds__(256) void build_wt_kernel(
    const float* __restrict__ W,
    const float* __restrict__ cayley,
    __bf16* __restrict__ Wt,
    int Cin, int Cout)
{
    __shared__ float Cay[512];
    for (int t = threadIdx.x; t < 512; t += 256) Cay[t] = cayley[t];
    __syncthreads();

    int flat = blockIdx.x * 256 + threadIdx.x;   // flat = n*Cin + i
    int total = Cout * 8 * Cin;
    if (flat >= total) return;
    int i = flat % Cin;
    int n = flat / Cin;
    int o = n >> 3, l = n & 7;

    const float* wrow = W + ((size_t)o * Cin + i) * 8;
    float w8[8];
    #pragma unroll
    for (int j = 0; j < 8; ++j) w8[j] = wrow[j];

    bf16x8 outv;
    #pragma unroll
    for (int k = 0; k < 8; ++k) {
        float s = 0.f;
        #pragma unroll
        for (int j = 0; j < 8; ++j) s += Cay[j * 64 + k * 8 + l] * w8[j];
        outv[k] = (__bf16)s;
    }
    *(bf16x8*)(Wt + (size_t)n * (Cin * 8) + i * 8) = outv;
}

// ---------------- kernel 3: bf16 GEMM, C = A * Bt^T + bias ----------------
// A  : [M][K] bf16 (row-major, pre-cast)
// Bt : [N][K] bf16 (row-major)
// C  : [M][N] fp32
//
// LDS layout (both A and B): tile row = 64 bf16 = 8 groups of 8 bf16 (16 B).
// Physical group p of row r holds GLOBAL group p ^ (r & 7)  (swizzle applied
// on the staging source address; global_load_lds scatter order untouched).
// Fragment read for MFMA k-half h, quad q, row l16:
//   global group = q + 4h  ->  physical offset ((q+4h) ^ (l16&7)) * 8.
// Bank check: row stride = 32 words (all rows start at bank 0); the 8
// distinct (l16&7) values spread the 16 lanes of a quad over all 8 bank
// groups, 2 lanes each -> 2-way aliasing, free (m136).
__global__ __launch_bounds__(256) void gemm_bt_kernel(
    const __bf16* __restrict__ A,
    const __bf16* __restrict__ Bt,
    const float*  __restrict__ bias,
    float* __restrict__ C,
    int M, int N, int K)
{
    __shared__ __align__(16) __bf16 As[BM * BK];  // 16 KB, swizzled [128][64]
    __shared__ __align__(16) __bf16 Bs[BN * BK];  // 16 KB, swizzled [128][64]

    const int tid  = threadIdx.x;
    const int wave = tid >> 6;
    const int lane = tid & 63;
    const int quad = lane >> 4;   // 0..3
    const int l16  = lane & 15;   // 0..15

    // --- XCD band swizzle: all 16 N-blocks of an M-band share bid%8 -> one XCD
    const int bid   = blockIdx.x;                    // 0..1023
    const int band  = (bid & 7) | ((bid >> 7) << 3); // 0..63
    const int ncol  = (bid >> 3) & 15;               // 0..15
    const int mBase = band * BM;
    const int nBase = ncol * BN;

    // --- staging: 1 KB chunk = 8 rows of 128 B; 16 chunks each for A and B;
    // wave w loads chunks 4w..4w+3 of both. XOR swizzle on source group.
    const int srow = lane >> 3;            // 0..7 row within chunk
    const int sgrp = (lane & 7) ^ srow;    // swizzled source 16B-group 0..7

    const __bf16* gA[4];
    const __bf16* gB[4];
    __bf16* lA[4];
    __bf16* lB[4];
    #pragma unroll
    for (int c = 0; c < 4; ++c) {
        const int chunk = 4 * wave + c;
        gA[c] = A  + (size_t)(mBase + chunk * 8 + srow) * K + sgrp * 8;
        gB[c] = Bt + (size_t)(nBase + chunk * 8 + srow) * K + sgrp * 8;
        lA[c] = As + chunk * 512;   // 512 bf16 = 1 KB
        lB[c] = Bs + chunk * 512;
    }

    // --- compute: wave quadrant (64x64), 4x4 grid of 16x16x32 MFMA tiles,
    // two k-halves (h=0: k 0..31, h=1: k 32..63) per BK iteration.
    const int wm = (wave >> 1) * 64;
    const int wn = (wave & 1) * 64;

    const int s     = l16 & 7;
    const int offH0 = ((quad)     ^ s) * 8;   // k-half 0: global group quad
    const int offH1 = ((quad + 4) ^ s) * 8;   // k-half 1: global group quad+4

    const __bf16* fragAbase = As + (size_t)(wm + l16) * BK;  // mt stride 16*64
    const __bf16* fragBbase = Bs + (size_t)(wn + l16) * BK;

    f32x4 acc[4][4] = {};

    for (int k0 = 0; k0 < K; k0 += BK) {
        __syncthreads();   // prior iteration's LDS reads done
        #pragma unroll
        for (int c = 0; c < 4; ++c) async_copy16(lA[c], gA[c] + k0);
        #pragma unroll
        for (int c = 0; c < 4; ++c) async_copy16(lB[c], gB[c] + k0);
        __syncthreads();   // vmcnt(0) drained before barrier by compiler

        // ---- k-half 0
        {
            bf16x8 af[4], bfr[4];
            #pragma unroll
            for (int mt = 0; mt < 4; ++mt)
                af[mt] = *(const bf16x8*)(fragAbase + mt * 16 * BK + offH0);
            #pragma unroll
            for (int nt = 0; nt < 4; ++nt)
                bfr[nt] = *(const bf16x8*)(fragBbase + nt * 16 * BK + offH0);
            #pragma unroll
            for (int mt = 0; mt < 4; ++mt)
                #pragma unroll
                for (int nt = 0; nt < 4; ++nt)
                    acc[mt][nt] = __builtin_amdgcn_mfma_f32_16x16x32_bf16(
                        af[mt], bfr[nt], acc[mt][nt], 0, 0, 0);
        }
        // ---- k-half 1
        {
            bf16x8 af[4], bfr[4];
            #pragma unroll
            for (int mt = 0; mt < 4; ++mt)
                af[mt] = *(const bf16x8*)(fragAbase + mt * 16 * BK + offH1);
            #pragma unroll
            for (int nt = 0; nt < 4; ++nt)
                bfr[nt] = *(const bf16x8*)(fragBbase + nt * 16 * BK + offH1);
            #pragma unroll
            for (int mt = 0; mt < 4; ++mt)
                #pragma unroll
                for (int nt = 0; nt < 4; ++nt)
                    acc[mt][nt] = __builtin_amdgcn_mfma_f32_16x16x32_bf16(
                        af[mt], bfr[nt], acc[mt][nt], 0, 0, 0);
        }
    }

    // --- epilogue: C/D layout col = lane&15, row = quad*4 + reg
    float bv[4];
    #pragma unroll
    for (int nt = 0; nt < 4; ++nt)
        bv[nt] = bias[nBase + wn + nt * 16 + l16];

    #pragma unroll
    for (int mt = 0; mt < 4; ++mt) {
        #pragma unroll
        for (int nt = 0; nt < 4; ++nt) {
            const int col = nBase + wn + nt * 16 + l16;
            #pragma unroll
            for (int r = 0; r < 4; ++r) {
                const int row = mBase + wm + mt * 16 + quad * 4 + r;
                C[(size_t)row * N + col] = acc[mt][nt][r] + bv[nt];
            }
        }
    }
}

extern "C" void kernel_launch(void* const* d_in, const int* in_sizes, int n_in,
                              void* d_out, int out_size, void* d_ws, size_t ws_size,
                              hipStream_t stream) {
    const float* x      = (const float*)d_in[0];  // [B][Cin][8]
    const float* weight = (const float*)d_in[1];  // [Cout][Cin][8]
    const float* bias   = (const float*)d_in[2];  // [Cout][8]
    const float* cayley = (const float*)d_in[3];  // [8][8][8]
    float* out = (float*)d_out;                   // [B][Cout][8]

    const int Cout = in_sizes[2] / 8;
    const int Cin  = in_sizes[1] / (Cout * 8);
    const int Bm   = in_sizes[0] / (Cin * 8);
    const int M = Bm;          // 8192
    const int N = Cout * 8;    // 2048
    const int K = Cin * 8;     // 2048

    __bf16* Xb = (__bf16*)d_ws;                               // M*K bf16 = 32 MB
    __bf16* Wt = (__bf16*)((char*)d_ws + (size_t)M * K * 2);  // N*K bf16 = 8 MB

    // 1) cast X to bf16
    long nx = (long)M * K;
    int castBlocks = (int)(nx / 8 / 256);   // nx divisible by 2048
    cast_bf16_kernel<<<castBlocks, 256, 0, stream>>>(x, Xb, nx);

    // 2) fold cayley into weight -> Wt [N][K] bf16
    int totalWt = N * Cin;
    build_wt_kernel<<<(totalWt + 255) / 256, 256, 0, stream>>>(weight, cayley, Wt, Cin, Cout);

    // 3) GEMM
    int grid = (M / BM) * (N / BN);   // 64 * 16 = 1024
    gemm_bt_kernel<<<grid, 256, 0, stream>>>(Xb, Wt, bias, out, M, N, K);
}